// Round 10
// baseline (315.148 us; speedup 1.0000x reference)
//
#include <hip/hip_runtime.h>

#define Bc 2
#define Sc 2048
#define Dc 2048
#define Hc 16
#define DHc 128

typedef _Float16 f16;
typedef __attribute__((ext_vector_type(4))) _Float16 v4h;
typedef __attribute__((ext_vector_type(8))) _Float16 v8h;
typedef __attribute__((ext_vector_type(4))) float v4f;
typedef __attribute__((ext_vector_type(16))) float v16f;
typedef __attribute__((ext_vector_type(4))) float f32x4;

// ---------------------------------------------------------------------------
// Convert f32 inputs -> f16 once. Round 10: BW-shaped rewrite.
// Total work = 20,971,520 f32 = 2,621,440 vec8 units = EXACTLY 5 x 524,288.
// Region boundaries (x: 2 steps, wq/wk/wv: 1 step each) align with the
// stride, so each step has a compile-time src/dst. 32B read + 16B write
// per lane per step (was 16B read + 8B write, 1 step, 20480 blocks).
// ---------------------------------------------------------------------------
__device__ __forceinline__ void cvt8(const float* __restrict__ src,
                                     f16* __restrict__ dst, int u)
{
    const f32x4* p = (const f32x4*)src + 2 * (size_t)u;
    f32x4 a = p[0], b = p[1];
    v8h hv;
    hv[0]=(f16)a[0]; hv[1]=(f16)a[1]; hv[2]=(f16)a[2]; hv[3]=(f16)a[3];
    hv[4]=(f16)b[0]; hv[5]=(f16)b[1]; hv[6]=(f16)b[2]; hv[7]=(f16)b[3];
    ((v8h*)dst)[u] = hv;
}

__global__ void cvt_kernel(const float* __restrict__ x, const float* __restrict__ wq,
                           const float* __restrict__ wk, const float* __restrict__ wv,
                           f16* __restrict__ xh, f16* __restrict__ wqh,
                           f16* __restrict__ wkh, f16* __restrict__ wvh)
{
    int t = blockIdx.x * 256 + threadIdx.x;      // 0 .. 524287
    cvt8(x,  xh,  t);
    cvt8(x,  xh,  t + 524288);
    cvt8(wq, wqh, t);
    cvt8(wk, wkh, t);
    cvt8(wv, wvh, t);
}

// ---------------------------------------------------------------------------
// Fused QKV projection GEMM C[4096][6144] = X . [wq;wk;wv]^T.
// 128x256 tile, BK=64, 8 waves, 768 blocks (3 exact rounds), T2 swizzle.
// r5 structure (best measured 124.9 us): 2 phases per K-tile, 3-buffer LDS
// ring, counted vmcnt(6). Unchanged this round.
// ---------------------------------------------------------------------------
__launch_bounds__(512, 2)
__global__ void proj256_kernel(const f16* __restrict__ xh, const f16* __restrict__ wall,
                               const float* __restrict__ cs, const float* __restrict__ sn,
                               f16* __restrict__ qh, f16* __restrict__ kh,
                               f16* __restrict__ vt)
{
    const int bid = blockIdx.x;
    const int swz = (bid & 7) * 96 + (bid >> 3);     // 768 % 8 == 0 -> bijective
    const int mt = swz & 31, nt = swz >> 5;
    const int m0 = mt * 128, n0 = nt * 256;

    const int tid = threadIdx.x;
    const int wid = tid >> 6, lane = tid & 63;
    const int wr = wid >> 2, wc = wid & 3;           // 2 x 4 waves
    const int l15 = lane & 15, quad = lane >> 4;
    const int x7 = l15 & 7;

    __shared__ __align__(16) f16 lds[73728];

    const f16* aS[2]; const f16* bS[4];
    #pragma unroll
    for (int j = 0; j < 2; ++j) {
        int c = tid + j * 512;
        int r = c >> 3, s = c & 7;
        aS[j] = xh + (size_t)(m0 + r) * Dc + ((s ^ (r & 7)) * 8);
    }
    #pragma unroll
    for (int j = 0; j < 4; ++j) {
        int c = tid + j * 512;
        int r = c >> 3, s = c & 7;
        bS[j] = wall + (size_t)(n0 + r) * Dc + ((s ^ (r & 7)) * 8);
    }

#define GLD(src_, dst_)                                                         \
    __builtin_amdgcn_global_load_lds(                                           \
        (const __attribute__((address_space(1))) void*)(src_),                  \
        (__attribute__((address_space(3))) void*)(dst_), 16, 0, 0)

#define STAGE_P0(kt_, buf_) do {                                                \
        const int _ko = (kt_) * 64;                                             \
        f16* _b = lds + (buf_) * 24576;                                         \
        GLD(aS[0] + _ko, _b + wid * 512);                                       \
        GLD(aS[1] + _ko, _b + 4096 + wid * 512);                                \
        GLD(bS[0] + _ko, _b + 8192 + wid * 512);                                \
    } while (0)

#define STAGE_P1(kt_, buf_) do {                                                \
        const int _ko = (kt_) * 64;                                             \
        f16* _b = lds + (buf_) * 24576;                                         \
        GLD(bS[1] + _ko, _b + 8192 + 4096  + wid * 512);                        \
        GLD(bS[2] + _ko, _b + 8192 + 8192  + wid * 512);                        \
        GLD(bS[3] + _ko, _b + 8192 + 12288 + wid * 512);                        \
    } while (0)

#define VMW6  asm volatile("s_waitcnt vmcnt(6)"  ::: "memory")
#define VMW0  asm volatile("s_waitcnt vmcnt(0)"  ::: "memory")
#define LGKM0 asm volatile("s_waitcnt lgkmcnt(0)" ::: "memory")
#define BAR   __builtin_amdgcn_s_barrier()

#define PHASE(kk_, bR_) do {                                                    \
        const f16* _Ab = lds + (bR_) * 24576;                                   \
        const f16* _Bb = _Ab + 8192;                                            \
        v8h af[4], bf[4];                                                       \
        _Pragma("unroll")                                                       \
        for (int mi = 0; mi < 4; ++mi)                                          \
            af[mi] = *(const v8h*)(_Ab + (wr * 64 + mi * 16 + l15) * 64         \
                                   + ((((kk_) * 4 + quad) ^ x7) * 8));          \
        _Pragma("unroll")                                                       \
        for (int ni = 0; ni < 4; ++ni)                                          \
            bf[ni] = *(const v8h*)(_Bb + (wc * 64 + ni * 16 + l15) * 64         \
                                   + ((((kk_) * 4 + quad) ^ x7) * 8));          \
        PH_TAIL;                                                                \
        __builtin_amdgcn_s_setprio(1);                                          \
        _Pragma("unroll")                                                       \
        for (int mi = 0; mi < 4; ++mi)                                          \
            _Pragma("unroll")                                                   \
            for (int ni = 0; ni < 4; ++ni)                                      \
                acc[mi][ni] = __builtin_amdgcn_mfma_f32_16x16x32_f16(           \
                    af[mi], bf[ni], acc[mi][ni], 0, 0, 0);                      \
        __builtin_amdgcn_s_setprio(0);                                          \
    } while (0)

    v4f acc[4][4];
    #pragma unroll
    for (int i = 0; i < 4; ++i)
        #pragma unroll
        for (int j = 0; j < 4; ++j)
            acc[i][j] = (v4f){0.f, 0.f, 0.f, 0.f};

    STAGE_P0(0, 0); STAGE_P1(0, 0);
    STAGE_P0(1, 1); STAGE_P1(1, 1);
    VMW6;
    BAR;

    int bR = 0;
    int bSt = 2;

    #pragma unroll 1
    for (int t = 0; t < 32; ++t) {
        {
#define PH_TAIL do { if (t + 2 < 32) STAGE_P0(t + 2, bSt); BAR; } while (0)
            PHASE(0, bR);
#undef PH_TAIL
        }
        BAR;
        {
#define PH_TAIL do { if (t + 2 < 32) STAGE_P1(t + 2, bSt);                      \
                     if (t < 30) { VMW6; } else { VMW0; }                       \
                     BAR; } while (0)
            PHASE(1, bR);
#undef PH_TAIL
        }
        LGKM0;
        BAR;

        bR  = (bR  == 2) ? 0 : bR  + 1;
        bSt = (bSt == 2) ? 0 : bSt + 1;
    }

#undef STAGE_P0
#undef STAGE_P1
#undef GLD
#undef VMW6
#undef VMW0
#undef LGKM0
#undef BAR
#undef PHASE

    const int z = n0 >> 11;
    const int bb = m0 >> 11, s0 = m0 & 2047;

    if (z < 2) {
        f16 (*Ep)[264] = (f16(*)[264])lds;
        #pragma unroll
        for (int mi = 0; mi < 4; ++mi)
            #pragma unroll
            for (int ni = 0; ni < 4; ++ni)
                #pragma unroll
                for (int r = 0; r < 4; ++r)
                    Ep[wr * 64 + mi * 16 + quad * 4 + r][wc * 64 + ni * 16 + l15] =
                        (f16)acc[mi][ni][r];
        __syncthreads();
        f16* outp = (z == 0) ? qh : kh;
        const float scl = (z == 0) ? 0.08838834764831845f : 1.0f;
        #pragma unroll
        for (int it = 0; it < 8; ++it) {
            int ch = tid + it * 512, row = ch >> 5, c = ch & 31;
            v8h val = *(const v8h*)&Ep[row][c * 8];
            int s = s0 + row;
            int nn = (n0 & 2047) + c * 8;
            int h = nn >> 7, d0 = nn & 127;
            const float* cp = cs + (size_t)s * DHc + d0;
            const float* sp = sn + (size_t)s * DHc + d0;
            f32x4 ca = *(const f32x4*)cp, cb = *(const f32x4*)(cp + 4);
            f32x4 sa = *(const f32x4*)sp, sb = *(const f32x4*)(sp + 4);
            float v[8];
            #pragma unroll
            for (int j = 0; j < 8; ++j) v[j] = (float)val[j];
            v8h rv;
            rv[0] = (f16)((v[0]*ca[0] - v[1]*sa[0]) * scl);
            rv[1] = (f16)((v[1]*ca[1] + v[0]*sa[1]) * scl);
            rv[2] = (f16)((v[2]*ca[2] - v[3]*sa[2]) * scl);
            rv[3] = (f16)((v[3]*ca[3] + v[2]*sa[3]) * scl);
            rv[4] = (f16)((v[4]*cb[0] - v[5]*sb[0]) * scl);
            rv[5] = (f16)((v[5]*cb[1] + v[4]*sb[1]) * scl);
            rv[6] = (f16)((v[6]*cb[2] - v[7]*sb[2]) * scl);
            rv[7] = (f16)((v[7]*cb[3] + v[6]*sb[3]) * scl);
            *(v8h*)(outp + ((size_t)(bb * Hc + h) * Sc + s) * DHc + d0) = rv;
        }
    } else {
        f16 (*Ep)[136] = (f16(*)[136])lds;
        #pragma unroll
        for (int mi = 0; mi < 4; ++mi)
            #pragma unroll
            for (int ni = 0; ni < 4; ++ni)
                #pragma unroll
                for (int r = 0; r < 4; ++r)
                    Ep[wc * 64 + ni * 16 + l15][wr * 64 + mi * 16 + quad * 4 + r] =
                        (f16)acc[mi][ni][r];
        __syncthreads();
        #pragma unroll
        for (int it = 0; it < 8; ++it) {
            int ch = tid + it * 512, n = ch >> 4, cm = ch & 15;
            int nn = (n0 & 2047) + n;
            int h = nn >> 7, d = nn & 127;
            int s = s0 + cm * 8;
            *(v8h*)(vt + ((size_t)(bb * Hc + h) * DHc + d) * Sc + s) =
                *(const v8h*)&Ep[n][cm * 8];
        }
    }
}

// ---------------------------------------------------------------------------
// Fallback proj (ws too small) + separate rope.
// ---------------------------------------------------------------------------
__launch_bounds__(256)
__global__ void proj_kernel(const float* __restrict__ x, const float* __restrict__ wq,
                            const float* __restrict__ wk, const float* __restrict__ wv,
                            f16* __restrict__ qh, f16* __restrict__ kh, f16* __restrict__ vt)
{
    const int z = blockIdx.z;
    const float* w = (z == 0) ? wq : ((z == 1) ? wk : wv);
    const int m0 = blockIdx.x * 128, n0 = blockIdx.y * 128;
    const int tid = threadIdx.x, lane = tid & 63, wid = tid >> 6;
    const int wm = wid >> 1, wn = wid & 1;
    const int l15 = lane & 15, quad = lane >> 4;

    __shared__ __align__(16) f16 smem[2 * 128 * 72];
    f16 (*As)[72] = (f16(*)[72])smem;
    f16 (*Bs)[72] = (f16(*)[72])(smem + 128 * 72);

    v4f acc[4][4];
    for (int i = 0; i < 4; ++i)
        for (int j = 0; j < 4; ++j)
            acc[i][j] = (v4f){0.f, 0.f, 0.f, 0.f};

    for (int k0 = 0; k0 < Dc; k0 += 64) {
        __syncthreads();
        for (int it = 0; it < 4; ++it) {
            int chunk = tid + it * 256;
            int r = chunk >> 3, cc = chunk & 7;
            const f32x4* pa = (const f32x4*)(x + (size_t)(m0 + r) * Dc + k0 + cc * 8);
            f32x4 a0 = pa[0], a1 = pa[1];
            v8h ha;
            ha[0]=(f16)a0[0]; ha[1]=(f16)a0[1]; ha[2]=(f16)a0[2]; ha[3]=(f16)a0[3];
            ha[4]=(f16)a1[0]; ha[5]=(f16)a1[1]; ha[6]=(f16)a1[2]; ha[7]=(f16)a1[3];
            *(v8h*)&As[r][cc * 8] = ha;
            const f32x4* pb = (const f32x4*)(w + (size_t)(n0 + r) * Dc + k0 + cc * 8);
            f32x4 b0 = pb[0], b1 = pb[1];
            v8h hb;
            hb[0]=(f16)b0[0]; hb[1]=(f16)b0[1]; hb[2]=(f16)b0[2]; hb[3]=(f16)b0[3];
            hb[4]=(f16)b1[0]; hb[5]=(f16)b1[1]; hb[6]=(f16)b1[2]; hb[7]=(f16)b1[3];
            *(v8h*)&Bs[r][cc * 8] = hb;
        }
        __syncthreads();
        for (int kk = 0; kk < 2; ++kk) {
            v8h af[4], bf[4];
            for (int mi = 0; mi < 4; ++mi)
                af[mi] = *(const v8h*)&As[wm * 64 + mi * 16 + l15][kk * 32 + quad * 8];
            for (int ni = 0; ni < 4; ++ni)
                bf[ni] = *(const v8h*)&Bs[wn * 64 + ni * 16 + l15][kk * 32 + quad * 8];
            for (int mi = 0; mi < 4; ++mi)
                for (int ni = 0; ni < 4; ++ni)
                    acc[mi][ni] = __builtin_amdgcn_mfma_f32_16x16x32_f16(
                        af[mi], bf[ni], acc[mi][ni], 0, 0, 0);
        }
    }
    __syncthreads();
    f16 (*Ep)[136] = (f16(*)[136])smem;
    for (int mi = 0; mi < 4; ++mi)
        for (int ni = 0; ni < 4; ++ni)
            for (int r = 0; r < 4; ++r) {
                int ml = wm * 64 + mi * 16 + quad * 4 + r;
                int nl = wn * 64 + ni * 16 + l15;
                f16 val = (f16)acc[mi][ni][r];
                if (z == 2) Ep[nl][ml] = val;
                else        Ep[ml][nl] = val;
            }
    __syncthreads();
    const int b = m0 >> 11, s0 = m0 & 2047, h = n0 >> 7;
    if (z < 2) {
        f16* outp = (z == 0) ? qh : kh;
        for (int it = 0; it < 8; ++it) {
            int ch = tid + it * 256, row = ch >> 4, c = ch & 15;
            *(v8h*)(outp + ((size_t)((b * Hc + h) * Sc) + s0 + row) * DHc + c * 8) =
                *(const v8h*)&Ep[row][c * 8];
        }
    } else {
        for (int it = 0; it < 8; ++it) {
            int ch = tid + it * 256, row = ch >> 4, c = ch & 15;
            *(v8h*)(vt + ((size_t)((b * Hc + h) * DHc) + row) * Sc + s0 + c * 8) =
                *(const v8h*)&Ep[row][c * 8];
        }
    }
}

__global__ void rope_kernel(f16* __restrict__ qh, f16* __restrict__ kh,
                            const float* __restrict__ cs, const float* __restrict__ sn)
{
    int i  = blockIdx.x * 256 + threadIdx.x;
    int d2 = i & 63;
    int s  = (i >> 6) & (Sc - 1);
    int bh = i >> 17;
    f16* t = blockIdx.y ? kh : qh;
    float scale = blockIdx.y ? 1.0f : 0.08838834764831845f;
    float c  = cs[s * DHc + 2 * d2];
    float sv = sn[s * DHc + 2 * d2];
    f16* p = t + ((size_t)bh * Sc + s) * DHc + 2 * d2;
    float t0 = (float)p[0], t1 = (float)p[1];
    p[0] = (f16)((t0 * c - t1 * sv) * scale);
    p[1] = (f16)((t1 * c + t0 * sv) * scale);
}

// ---------------------------------------------------------------------------
// Flash attention v10: v9 balanced 8-wave split + T5 setprio around MFMA
// clusters (m191: +4-7% for independent-wave attn) + 4-way tree softmax sum
// (breaks the 32-deep serial add chain). Structure otherwise identical to v9.
// ---------------------------------------------------------------------------
__launch_bounds__(512, 2)
__global__ void attn_kernel(const f16* __restrict__ qh, const f16* __restrict__ kh,
                            const f16* __restrict__ vt, float* __restrict__ out)
{
    const int L = blockIdx.x;
    const int slot = L >> 3;
    const int bh = (L & 7) * 4 + (slot >> 3);
    const int p  = slot & 7;
    const int b = bh >> 4, h = bh & 15;
    const int tid = threadIdx.x, lane = tid & 63, w = tid >> 6;
    const int grp = w >> 2, wg = w & 3;
    const int l31 = lane & 31, half = lane >> 5;
    const int sw = l31 & 7;

    __shared__ __align__(16) f16 smem[65536];
    f16* gbase = smem + grp * 32768;
    f16* ksm = gbase;             // K dbuf: 2 x 8192 f16
    f16* vsm = gbase + 16384;     // V dbuf: 2 x 8192 f16

    const size_t bhoff = (size_t)bh * Sc * DHc;

    const f16* ksrc[4]; const f16* vsrc[4];
    f16* kdst[4]; f16* vdst[4];
    #pragma unroll
    for (int j = 0; j < 4; ++j) {
        int slot0 = j * 256 + wg * 64;
        {   int r = (slot0 >> 4) + (lane >> 4);
            int c = (lane & 15) ^ (r & 7);
            ksrc[j] = kh + bhoff + (size_t)r * DHc + c * 8;
            kdst[j] = ksm + slot0 * 8; }
        {   int r = (slot0 >> 3) + (lane >> 3);
            int c = (lane & 7) ^ (r & 7);
            vsrc[j] = vt + bhoff + (size_t)r * Sc + c * 8;
            vdst[j] = vsm + slot0 * 8; }
    }

#define STAGE(kt_, buf_) do {                                                   \
        int _ko = (kt_) * 64 * DHc;                                             \
        int _vo = (kt_) * 64;                                                   \
        int _lb = (buf_) * 8192;                                                \
        _Pragma("unroll")                                                       \
        for (int j = 0; j < 4; ++j) {                                           \
            __builtin_amdgcn_global_load_lds(                                   \
                (const __attribute__((address_space(1))) void*)(ksrc[j] + _ko), \
                (__attribute__((address_space(3))) void*)(kdst[j] + _lb), 16, 0, 0); \
            __builtin_amdgcn_global_load_lds(                                   \
                (const __attribute__((address_space(1))) void*)(vsrc[j] + _vo), \
                (__attribute__((address_space(3))) void*)(vdst[j] + _lb), 16, 0, 0); \
        } } while (0)

#define EPILOG do {                                                             \
        float inv = 1.f / l_run;                                               \
        float mxd = -1e30f;                                                    \
        _Pragma("unroll")                                                      \
        for (int dt = 0; dt < 4; ++dt)                                         \
            _Pragma("unroll")                                                  \
            for (int r = 0; r < 16; ++r) {                                     \
                o[dt][r] *= inv;                                               \
                mxd = fmaxf(mxd, o[dt][r]);                                    \
            }                                                                  \
        mxd = fmaxf(mxd, __shfl_xor(mxd, 32));                                 \
        float sd = 0.f;                                                        \
        _Pragma("unroll")                                                      \
        for (int dt = 0; dt < 4; ++dt)                                         \
            _Pragma("unroll")                                                  \
            for (int r = 0; r < 16; ++r) {                                     \
                float tv = __expf(o[dt][r] - mxd);                             \
                o[dt][r] = tv;                                                 \
                sd += tv;                                                      \
            }                                                                  \
        sd += __shfl_xor(sd, 32);                                              \
        float rinv = 1.f / sd;                                                 \
        float* orow = out + (size_t)(b * Sc + qg) * Dc + h * DHc;              \
        _Pragma("unroll")                                                      \
        for (int dt = 0; dt < 4; ++dt)                                         \
            _Pragma("unroll")                                                  \
            for (int g2 = 0; g2 < 4; ++g2) {                                   \
                f32x4 vv;                                                      \
                vv[0] = o[dt][4*g2+0] * rinv;                                  \
                vv[1] = o[dt][4*g2+1] * rinv;                                  \
                vv[2] = o[dt][4*g2+2] * rinv;                                  \
                vv[3] = o[dt][4*g2+3] * rinv;                                  \
                *(f32x4*)(orow + dt * 32 + g2 * 8 + half * 4) = vv;            \
            }                                                                  \
    } while (0)

    const int tp_end = 2 * p + 2;
    const int tailoff = 15 - 2 * p;

    int qt = grp ? p : (15 - p);
    int q0 = qt * 128 + wg * 32;
    int qg = q0 + l31;

    v8h qf[8];
    {
        const f16* qrow = qh + bhoff + (size_t)qg * DHc;
        #pragma unroll
        for (int s = 0; s < 8; ++s)
            qf[s] = *(const v8h*)(qrow + s * 16 + half * 8);
    }

    float l_run = 0.f;
    v16f o[4];
    #pragma unroll
    for (int i = 0; i < 4; ++i)
        #pragma unroll
        for (int r = 0; r < 16; ++r) o[i][r] = 0.f;

    STAGE(0, 0);

    #pragma unroll 1
    for (int i = 0; i < 17; ++i) {
        __syncthreads();
        if (i < 16) {
            int inx = i + 1;
            int kn = (grp == 0) ? inx : ((inx < tp_end) ? inx : inx + tailoff);
            STAGE(kn, inx & 1);
        }
        if (grp == 1 && i == tp_end) {
            EPILOG;
            l_run = 0.f;
            #pragma unroll
            for (int d2 = 0; d2 < 4; ++d2)
                #pragma unroll
                for (int r = 0; r < 16; ++r) o[d2][r] = 0.f;
            qt = 15 - p; q0 = qt * 128 + wg * 32; qg = q0 + l31;
            const f16* qrow = qh + bhoff + (size_t)qg * DHc;
            #pragma unroll
            for (int s = 0; s < 8; ++s)
                qf[s] = *(const v8h*)(qrow + s * 16 + half * 8);
        }
        const int kv = (grp == 0) ? i : ((i < tp_end) ? i : i + tailoff);
        if (q0 + 31 < kv * 64) continue;

        const f16* kbuf = ksm + (i & 1) * 8192;
        const f16* vbuf = vsm + (i & 1) * 8192;
        const bool do1 = (kv * 64 + 32 <= q0 + 31);

        v16f st0, st1;
        #pragma unroll
        for (int r = 0; r < 16; ++r) { st0[r] = 0.f; st1[r] = 0.f; }
        __builtin_amdgcn_s_setprio(1);
        #pragma unroll
        for (int s = 0; s < 8; ++s) {
            int c = ((s * 2 + half) ^ sw) * 8;
            v8h kf0 = *(const v8h*)(kbuf + l31 * 128 + c);
            st0 = __builtin_amdgcn_mfma_f32_32x32x16_f16(kf0, qf[s], st0, 0, 0, 0);
            if (do1) {
                v8h kf1 = *(const v8h*)(kbuf + (32 + l31) * 128 + c);
                st1 = __builtin_amdgcn_mfma_f32_32x32x16_f16(kf1, qf[s], st1, 0, 0, 0);
            }
        }
        __builtin_amdgcn_s_setprio(0);

        // 4-way tree softmax sum (breaks the 32-deep serial add chain)
        float sa0 = 0.f, sa1 = 0.f, sa2 = 0.f, sa3 = 0.f;
        #pragma unroll
        for (int r = 0; r < 16; ++r) {
            int key = kv * 64 + (r & 3) + 8 * (r >> 2) + 4 * half;
            float sv = (key > qg) ? -1e30f : st0[r];
            float pe = __expf(sv);
            st0[r] = pe;
            if ((r & 3) == 0) sa0 += pe;
            else if ((r & 3) == 1) sa1 += pe;
            else if ((r & 3) == 2) sa2 += pe;
            else sa3 += pe;
        }
        if (do1) {
            #pragma unroll
            for (int r = 0; r < 16; ++r) {
                int key = kv * 64 + 32 + (r & 3) + 8 * (r >> 2) + 4 * half;
                float sv = (key > qg) ? -1e30f : st1[r];
                float pe = __expf(sv);
                st1[r] = pe;
                if ((r & 3) == 0) sa0 += pe;
                else if ((r & 3) == 1) sa1 += pe;
                else if ((r & 3) == 2) sa2 += pe;
                else sa3 += pe;
            }
        }
        float sum = (sa0 + sa1) + (sa2 + sa3);
        sum += __shfl_xor(sum, 32);
        l_run += sum;

        __builtin_amdgcn_s_setprio(1);
        #pragma unroll
        for (int s2 = 0; s2 < 4; ++s2) {
            v4h bfr;
            bfr[0]=(f16)st0[4*s2]; bfr[1]=(f16)st0[4*s2+1];
            bfr[2]=(f16)st0[4*s2+2]; bfr[3]=(f16)st0[4*s2+3];
            int c = ((s2 ^ sw) * 8) + half * 4;
            #pragma unroll
            for (int dt = 0; dt < 4; ++dt) {
                v4h vf = *(const v4h*)(vbuf + (dt * 32 + l31) * 64 + c);
                o[dt] = __builtin_amdgcn_mfma_f32_32x32x8f16(vf, bfr, o[dt], 0, 0, 0);
            }
        }
        if (do1) {
            #pragma unroll
            for (int s2 = 0; s2 < 4; ++s2) {
                v4h bfr;
                bfr[0]=(f16)st1[4*s2]; bfr[1]=(f16)st1[4*s2+1];
                bfr[2]=(f16)st1[4*s2+2]; bfr[3]=(f16)st1[4*s2+3];
                int c = (((4 + s2) ^ sw) * 8) + half * 4;
                #pragma unroll
                for (int dt = 0; dt < 4; ++dt) {
                    v4h vf = *(const v4h*)(vbuf + (dt * 32 + l31) * 64 + c);
                    o[dt] = __builtin_amdgcn_mfma_f32_32x32x8f16(vf, bfr, o[dt], 0, 0, 0);
                }
            }
        }
        __builtin_amdgcn_s_setprio(0);
    }

    // ---- combine: g1's tile-A partial -> g0, then g0 epilogues tile A ----
    __syncthreads();
    float* ox = (float*)smem;
    float* lx = (float*)smem + 16384;
    if (grp == 1) {
        #pragma unroll
        for (int dt = 0; dt < 4; ++dt)
            #pragma unroll
            for (int r = 0; r < 16; ++r)
                ox[wg * 4096 + (dt * 16 + r) * 64 + lane] = o[dt][r];
        lx[wg * 64 + lane] = l_run;
    }
    __syncthreads();
    if (grp == 0) {
        #pragma unroll
        for (int dt = 0; dt < 4; ++dt)
            #pragma unroll
            for (int r = 0; r < 16; ++r)
                o[dt][r] += ox[wg * 4096 + (dt * 16 + r) * 64 + lane];
        l_run += lx[wg * 64 + lane];
        EPILOG;
    }
#undef STAGE
#undef EPILOG
}

extern "C" void kernel_launch(void* const* d_in, const int* in_sizes, int n_in,
                              void* d_out, int out_size, void* d_ws, size_t ws_size,
                              hipStream_t stream)
{
    const float* x  = (const float*)d_in[0];
    const float* wq = (const float*)d_in[1];
    const float* wk = (const float*)d_in[2];
    const float* wv = (const float*)d_in[3];
    const float* cs = (const float*)d_in[4];
    const float* sn = (const float*)d_in[5];
    float* out = (float*)d_out;

    const size_t tsz = (size_t)Bc * Hc * Sc * DHc;   // 8,388,608 halves
    f16* qh = (f16*)d_ws;
    f16* kh = qh + tsz;
    f16* vt = kh + tsz;

    if (ws_size >= 11 * tsz) {
        f16* xh  = vt + tsz;
        f16* wqh = xh + tsz;
        f16* wkh = wqh + tsz / 2;
        f16* wvh = wkh + tsz / 2;
        cvt_kernel<<<2048, 256, 0, stream>>>(x, wq, wk, wv, xh, wqh, wkh, wvh);
        // wqh/wkh/wvh are contiguous -> one stacked-W GEMM, N = 6144
        proj256_kernel<<<768, 512, 0, stream>>>(xh, wqh, cs, sn, qh, kh, vt);
    } else {
        proj_kernel<<<dim3(32, 16, 3), 256, 0, stream>>>(x, wq, wk, wv, qh, kh, vt);
        rope_kernel<<<dim3(16384, 2), 256, 0, stream>>>(qh, kh, cs, sn);
    }
    attn_kernel<<<256, 512, 0, stream>>>(qh, kh, vt, out);
}

// Round 12
// 307.617 us; speedup vs baseline: 1.0245x; 1.0245x over previous
//
#include <hip/hip_runtime.h>

#define Bc 2
#define Sc 2048
#define Dc 2048
#define Hc 16
#define DHc 128

typedef _Float16 f16;
typedef __attribute__((ext_vector_type(2))) __fp16 v2hf;
typedef __attribute__((ext_vector_type(4))) _Float16 v4h;
typedef __attribute__((ext_vector_type(8))) _Float16 v8h;
typedef __attribute__((ext_vector_type(4))) float v4f;
typedef __attribute__((ext_vector_type(16))) float v16f;
typedef __attribute__((ext_vector_type(4))) float f32x4;

// ---------------------------------------------------------------------------
// Convert f32 inputs -> f16 once. BW-shaped: 2048 blocks, 5 compile-time
// steps/thread, 32B read + 16B write per lane per step.
// ---------------------------------------------------------------------------
__device__ __forceinline__ void cvt8(const float* __restrict__ src,
                                     f16* __restrict__ dst, int u)
{
    const f32x4* p = (const f32x4*)src + 2 * (size_t)u;
    f32x4 a = p[0], b = p[1];
    v8h hv;
    hv[0]=(f16)a[0]; hv[1]=(f16)a[1]; hv[2]=(f16)a[2]; hv[3]=(f16)a[3];
    hv[4]=(f16)b[0]; hv[5]=(f16)b[1]; hv[6]=(f16)b[2]; hv[7]=(f16)b[3];
    ((v8h*)dst)[u] = hv;
}

__global__ void cvt_kernel(const float* __restrict__ x, const float* __restrict__ wq,
                           const float* __restrict__ wk, const float* __restrict__ wv,
                           f16* __restrict__ xh, f16* __restrict__ wqh,
                           f16* __restrict__ wkh, f16* __restrict__ wvh)
{
    int t = blockIdx.x * 256 + threadIdx.x;      // 0 .. 524287
    cvt8(x,  xh,  t);
    cvt8(x,  xh,  t + 524288);
    cvt8(wq, wqh, t);
    cvt8(wk, wkh, t);
    cvt8(wv, wvh, t);
}

// ---------------------------------------------------------------------------
// Fused QKV projection GEMM C[4096][6144] = X . [wq;wk;wv]^T.
// 128x256 tile, BK=64, 8 waves, 768 blocks (3 exact rounds), T2 swizzle.
// r5 structure (best measured 124.9 us): 2 phases per K-tile, 3-buffer LDS
// ring, counted vmcnt(6). Unchanged.
// ---------------------------------------------------------------------------
__launch_bounds__(512, 2)
__global__ void proj256_kernel(const f16* __restrict__ xh, const f16* __restrict__ wall,
                               const float* __restrict__ cs, const float* __restrict__ sn,
                               f16* __restrict__ qh, f16* __restrict__ kh,
                               f16* __restrict__ vt)
{
    const int bid = blockIdx.x;
    const int swz = (bid & 7) * 96 + (bid >> 3);     // 768 % 8 == 0 -> bijective
    const int mt = swz & 31, nt = swz >> 5;
    const int m0 = mt * 128, n0 = nt * 256;

    const int tid = threadIdx.x;
    const int wid = tid >> 6, lane = tid & 63;
    const int wr = wid >> 2, wc = wid & 3;           // 2 x 4 waves
    const int l15 = lane & 15, quad = lane >> 4;
    const int x7 = l15 & 7;

    __shared__ __align__(16) f16 lds[73728];

    const f16* aS[2]; const f16* bS[4];
    #pragma unroll
    for (int j = 0; j < 2; ++j) {
        int c = tid + j * 512;
        int r = c >> 3, s = c & 7;
        aS[j] = xh + (size_t)(m0 + r) * Dc + ((s ^ (r & 7)) * 8);
    }
    #pragma unroll
    for (int j = 0; j < 4; ++j) {
        int c = tid + j * 512;
        int r = c >> 3, s = c & 7;
        bS[j] = wall + (size_t)(n0 + r) * Dc + ((s ^ (r & 7)) * 8);
    }

#define GLD(src_, dst_)                                                         \
    __builtin_amdgcn_global_load_lds(                                           \
        (const __attribute__((address_space(1))) void*)(src_),                  \
        (__attribute__((address_space(3))) void*)(dst_), 16, 0, 0)

#define STAGE_P0(kt_, buf_) do {                                                \
        const int _ko = (kt_) * 64;                                             \
        f16* _b = lds + (buf_) * 24576;                                         \
        GLD(aS[0] + _ko, _b + wid * 512);                                       \
        GLD(aS[1] + _ko, _b + 4096 + wid * 512);                                \
        GLD(bS[0] + _ko, _b + 8192 + wid * 512);                                \
    } while (0)

#define STAGE_P1(kt_, buf_) do {                                                \
        const int _ko = (kt_) * 64;                                             \
        f16* _b = lds + (buf_) * 24576;                                         \
        GLD(bS[1] + _ko, _b + 8192 + 4096  + wid * 512);                        \
        GLD(bS[2] + _ko, _b + 8192 + 8192  + wid * 512);                        \
        GLD(bS[3] + _ko, _b + 8192 + 12288 + wid * 512);                        \
    } while (0)

#define VMW6  asm volatile("s_waitcnt vmcnt(6)"  ::: "memory")
#define VMW0  asm volatile("s_waitcnt vmcnt(0)"  ::: "memory")
#define LGKM0 asm volatile("s_waitcnt lgkmcnt(0)" ::: "memory")
#define BAR   __builtin_amdgcn_s_barrier()

#define PHASE(kk_, bR_) do {                                                    \
        const f16* _Ab = lds + (bR_) * 24576;                                   \
        const f16* _Bb = _Ab + 8192;                                            \
        v8h af[4], bf[4];                                                       \
        _Pragma("unroll")                                                       \
        for (int mi = 0; mi < 4; ++mi)                                          \
            af[mi] = *(const v8h*)(_Ab + (wr * 64 + mi * 16 + l15) * 64         \
                                   + ((((kk_) * 4 + quad) ^ x7) * 8));          \
        _Pragma("unroll")                                                       \
        for (int ni = 0; ni < 4; ++ni)                                          \
            bf[ni] = *(const v8h*)(_Bb + (wc * 64 + ni * 16 + l15) * 64         \
                                   + ((((kk_) * 4 + quad) ^ x7) * 8));          \
        PH_TAIL;                                                                \
        __builtin_amdgcn_s_setprio(1);                                          \
        _Pragma("unroll")                                                       \
        for (int mi = 0; mi < 4; ++mi)                                          \
            _Pragma("unroll")                                                   \
            for (int ni = 0; ni < 4; ++ni)                                      \
                acc[mi][ni] = __builtin_amdgcn_mfma_f32_16x16x32_f16(           \
                    af[mi], bf[ni], acc[mi][ni], 0, 0, 0);                      \
        __builtin_amdgcn_s_setprio(0);                                          \
    } while (0)

    v4f acc[4][4];
    #pragma unroll
    for (int i = 0; i < 4; ++i)
        #pragma unroll
        for (int j = 0; j < 4; ++j)
            acc[i][j] = (v4f){0.f, 0.f, 0.f, 0.f};

    STAGE_P0(0, 0); STAGE_P1(0, 0);
    STAGE_P0(1, 1); STAGE_P1(1, 1);
    VMW6;
    BAR;

    int bR = 0;
    int bSt = 2;

    #pragma unroll 1
    for (int t = 0; t < 32; ++t) {
        {
#define PH_TAIL do { if (t + 2 < 32) STAGE_P0(t + 2, bSt); BAR; } while (0)
            PHASE(0, bR);
#undef PH_TAIL
        }
        BAR;
        {
#define PH_TAIL do { if (t + 2 < 32) STAGE_P1(t + 2, bSt);                      \
                     if (t < 30) { VMW6; } else { VMW0; }                       \
                     BAR; } while (0)
            PHASE(1, bR);
#undef PH_TAIL
        }
        LGKM0;
        BAR;

        bR  = (bR  == 2) ? 0 : bR  + 1;
        bSt = (bSt == 2) ? 0 : bSt + 1;
    }

#undef STAGE_P0
#undef STAGE_P1
#undef GLD
#undef VMW6
#undef VMW0
#undef LGKM0
#undef BAR
#undef PHASE

    const int z = n0 >> 11;
    const int bb = m0 >> 11, s0 = m0 & 2047;

    if (z < 2) {
        f16 (*Ep)[264] = (f16(*)[264])lds;
        #pragma unroll
        for (int mi = 0; mi < 4; ++mi)
            #pragma unroll
            for (int ni = 0; ni < 4; ++ni)
                #pragma unroll
                for (int r = 0; r < 4; ++r)
                    Ep[wr * 64 + mi * 16 + quad * 4 + r][wc * 64 + ni * 16 + l15] =
                        (f16)acc[mi][ni][r];
        __syncthreads();
        f16* outp = (z == 0) ? qh : kh;
        const float scl = (z == 0) ? 0.08838834764831845f : 1.0f;
        #pragma unroll
        for (int it = 0; it < 8; ++it) {
            int ch = tid + it * 512, row = ch >> 5, c = ch & 31;
            v8h val = *(const v8h*)&Ep[row][c * 8];
            int s = s0 + row;
            int nn = (n0 & 2047) + c * 8;
            int h = nn >> 7, d0 = nn & 127;
            const float* cp = cs + (size_t)s * DHc + d0;
            const float* sp = sn + (size_t)s * DHc + d0;
            f32x4 ca = *(const f32x4*)cp, cb = *(const f32x4*)(cp + 4);
            f32x4 sa = *(const f32x4*)sp, sb = *(const f32x4*)(sp + 4);
            float v[8];
            #pragma unroll
            for (int j = 0; j < 8; ++j) v[j] = (float)val[j];
            v8h rv;
            rv[0] = (f16)((v[0]*ca[0] - v[1]*sa[0]) * scl);
            rv[1] = (f16)((v[1]*ca[1] + v[0]*sa[1]) * scl);
            rv[2] = (f16)((v[2]*ca[2] - v[3]*sa[2]) * scl);
            rv[3] = (f16)((v[3]*ca[3] + v[2]*sa[3]) * scl);
            rv[4] = (f16)((v[4]*cb[0] - v[5]*sb[0]) * scl);
            rv[5] = (f16)((v[5]*cb[1] + v[4]*sb[1]) * scl);
            rv[6] = (f16)((v[6]*cb[2] - v[7]*sb[2]) * scl);
            rv[7] = (f16)((v[7]*cb[3] + v[6]*sb[3]) * scl);
            *(v8h*)(outp + ((size_t)(bb * Hc + h) * Sc + s) * DHc + d0) = rv;
        }
    } else {
        f16 (*Ep)[136] = (f16(*)[136])lds;
        #pragma unroll
        for (int mi = 0; mi < 4; ++mi)
            #pragma unroll
            for (int ni = 0; ni < 4; ++ni)
                #pragma unroll
                for (int r = 0; r < 4; ++r)
                    Ep[wc * 64 + ni * 16 + l15][wr * 64 + mi * 16 + quad * 4 + r] =
                        (f16)acc[mi][ni][r];
        __syncthreads();
        #pragma unroll
        for (int it = 0; it < 8; ++it) {
            int ch = tid + it * 512, n = ch >> 4, cm = ch & 15;
            int nn = (n0 & 2047) + n;
            int h = nn >> 7, d = nn & 127;
            int s = s0 + cm * 8;
            *(v8h*)(vt + ((size_t)(bb * Hc + h) * DHc + d) * Sc + s) =
                *(const v8h*)&Ep[n][cm * 8];
        }
    }
}

// ---------------------------------------------------------------------------
// Fallback proj (ws too small) + separate rope.
// ---------------------------------------------------------------------------
__launch_bounds__(256)
__global__ void proj_kernel(const float* __restrict__ x, const float* __restrict__ wq,
                            const float* __restrict__ wk, const float* __restrict__ wv,
                            f16* __restrict__ qh, f16* __restrict__ kh, f16* __restrict__ vt)
{
    const int z = blockIdx.z;
    const float* w = (z == 0) ? wq : ((z == 1) ? wk : wv);
    const int m0 = blockIdx.x * 128, n0 = blockIdx.y * 128;
    const int tid = threadIdx.x, lane = tid & 63, wid = tid >> 6;
    const int wm = wid >> 1, wn = wid & 1;
    const int l15 = lane & 15, quad = lane >> 4;

    __shared__ __align__(16) f16 smem[2 * 128 * 72];
    f16 (*As)[72] = (f16(*)[72])smem;
    f16 (*Bs)[72] = (f16(*)[72])(smem + 128 * 72);

    v4f acc[4][4];
    for (int i = 0; i < 4; ++i)
        for (int j = 0; j < 4; ++j)
            acc[i][j] = (v4f){0.f, 0.f, 0.f, 0.f};

    for (int k0 = 0; k0 < Dc; k0 += 64) {
        __syncthreads();
        for (int it = 0; it < 4; ++it) {
            int chunk = tid + it * 256;
            int r = chunk >> 3, cc = chunk & 7;
            const f32x4* pa = (const f32x4*)(x + (size_t)(m0 + r) * Dc + k0 + cc * 8);
            f32x4 a0 = pa[0], a1 = pa[1];
            v8h ha;
            ha[0]=(f16)a0[0]; ha[1]=(f16)a0[1]; ha[2]=(f16)a0[2]; ha[3]=(f16)a0[3];
            ha[4]=(f16)a1[0]; ha[5]=(f16)a1[1]; ha[6]=(f16)a1[2]; ha[7]=(f16)a1[3];
            *(v8h*)&As[r][cc * 8] = ha;
            const f32x4* pb = (const f32x4*)(w + (size_t)(n0 + r) * Dc + k0 + cc * 8);
            f32x4 b0 = pb[0], b1 = pb[1];
            v8h hb;
            hb[0]=(f16)b0[0]; hb[1]=(f16)b0[1]; hb[2]=(f16)b0[2]; hb[3]=(f16)b0[3];
            hb[4]=(f16)b1[0]; hb[5]=(f16)b1[1]; hb[6]=(f16)b1[2]; hb[7]=(f16)b1[3];
            *(v8h*)&Bs[r][cc * 8] = hb;
        }
        __syncthreads();
        for (int kk = 0; kk < 2; ++kk) {
            v8h af[4], bf[4];
            for (int mi = 0; mi < 4; ++mi)
                af[mi] = *(const v8h*)&As[wm * 64 + mi * 16 + l15][kk * 32 + quad * 8];
            for (int ni = 0; ni < 4; ++ni)
                bf[ni] = *(const v8h*)&Bs[wn * 64 + ni * 16 + l15][kk * 32 + quad * 8];
            for (int mi = 0; mi < 4; ++mi)
                for (int ni = 0; ni < 4; ++ni)
                    acc[mi][ni] = __builtin_amdgcn_mfma_f32_16x16x32_f16(
                        af[mi], bf[ni], acc[mi][ni], 0, 0, 0);
        }
    }
    __syncthreads();
    f16 (*Ep)[136] = (f16(*)[136])smem;
    for (int mi = 0; mi < 4; ++mi)
        for (int ni = 0; ni < 4; ++ni)
            for (int r = 0; r < 4; ++r) {
                int ml = wm * 64 + mi * 16 + quad * 4 + r;
                int nl = wn * 64 + ni * 16 + l15;
                f16 val = (f16)acc[mi][ni][r];
                if (z == 2) Ep[nl][ml] = val;
                else        Ep[ml][nl] = val;
            }
    __syncthreads();
    const int b = m0 >> 11, s0 = m0 & 2047, h = n0 >> 7;
    if (z < 2) {
        f16* outp = (z == 0) ? qh : kh;
        for (int it = 0; it < 8; ++it) {
            int ch = tid + it * 256, row = ch >> 4, c = ch & 15;
            *(v8h*)(outp + ((size_t)((b * Hc + h) * Sc) + s0 + row) * DHc + c * 8) =
                *(const v8h*)&Ep[row][c * 8];
        }
    } else {
        for (int it = 0; it < 8; ++it) {
            int ch = tid + it * 256, row = ch >> 4, c = ch & 15;
            *(v8h*)(vt + ((size_t)((b * Hc + h) * DHc) + row) * Sc + s0 + c * 8) =
                *(const v8h*)&Ep[row][c * 8];
        }
    }
}

__global__ void rope_kernel(f16* __restrict__ qh, f16* __restrict__ kh,
                            const float* __restrict__ cs, const float* __restrict__ sn)
{
    int i  = blockIdx.x * 256 + threadIdx.x;
    int d2 = i & 63;
    int s  = (i >> 6) & (Sc - 1);
    int bh = i >> 17;
    f16* t = blockIdx.y ? kh : qh;
    float scale = blockIdx.y ? 1.0f : 0.08838834764831845f;
    float c  = cs[s * DHc + 2 * d2];
    float sv = sn[s * DHc + 2 * d2];
    f16* p = t + ((size_t)bh * Sc + s) * DHc + 2 * d2;
    float t0 = (float)p[0], t1 = (float)p[1];
    p[0] = (f16)((t0 * c - t1 * sv) * scale);
    p[1] = (f16)((t1 * c + t0 * sv) * scale);
}

// ---------------------------------------------------------------------------
// Flash attention v11: exact v9 structure (balanced 8-wave split, 17 lockstep
// iters, no setprio). One change vs v9: P->f16 packing via v_cvt_pkrtz
// (1 instr per f32 pair, was 4 scalar cvt+pack). v2hf typedef fixes the
// __fp16-vs-_Float16 return-type mismatch from r11.
// ---------------------------------------------------------------------------
__launch_bounds__(512, 2)
__global__ void attn_kernel(const f16* __restrict__ qh, const f16* __restrict__ kh,
                            const f16* __restrict__ vt, float* __restrict__ out)
{
    const int L = blockIdx.x;
    const int slot = L >> 3;
    const int bh = (L & 7) * 4 + (slot >> 3);
    const int p  = slot & 7;
    const int b = bh >> 4, h = bh & 15;
    const int tid = threadIdx.x, lane = tid & 63, w = tid >> 6;
    const int grp = w >> 2, wg = w & 3;
    const int l31 = lane & 31, half = lane >> 5;
    const int sw = l31 & 7;

    __shared__ __align__(16) f16 smem[65536];
    f16* gbase = smem + grp * 32768;
    f16* ksm = gbase;             // K dbuf: 2 x 8192 f16
    f16* vsm = gbase + 16384;     // V dbuf: 2 x 8192 f16

    const size_t bhoff = (size_t)bh * Sc * DHc;

    const f16* ksrc[4]; const f16* vsrc[4];
    f16* kdst[4]; f16* vdst[4];
    #pragma unroll
    for (int j = 0; j < 4; ++j) {
        int slot0 = j * 256 + wg * 64;
        {   int r = (slot0 >> 4) + (lane >> 4);
            int c = (lane & 15) ^ (r & 7);
            ksrc[j] = kh + bhoff + (size_t)r * DHc + c * 8;
            kdst[j] = ksm + slot0 * 8; }
        {   int r = (slot0 >> 3) + (lane >> 3);
            int c = (lane & 7) ^ (r & 7);
            vsrc[j] = vt + bhoff + (size_t)r * Sc + c * 8;
            vdst[j] = vsm + slot0 * 8; }
    }

#define STAGE(kt_, buf_) do {                                                   \
        int _ko = (kt_) * 64 * DHc;                                             \
        int _vo = (kt_) * 64;                                                   \
        int _lb = (buf_) * 8192;                                                \
        _Pragma("unroll")                                                       \
        for (int j = 0; j < 4; ++j) {                                           \
            __builtin_amdgcn_global_load_lds(                                   \
                (const __attribute__((address_space(1))) void*)(ksrc[j] + _ko), \
                (__attribute__((address_space(3))) void*)(kdst[j] + _lb), 16, 0, 0); \
            __builtin_amdgcn_global_load_lds(                                   \
                (const __attribute__((address_space(1))) void*)(vsrc[j] + _vo), \
                (__attribute__((address_space(3))) void*)(vdst[j] + _lb), 16, 0, 0); \
        } } while (0)

#define EPILOG do {                                                             \
        float inv = 1.f / l_run;                                               \
        float mxd = -1e30f;                                                    \
        _Pragma("unroll")                                                      \
        for (int dt = 0; dt < 4; ++dt)                                         \
            _Pragma("unroll")                                                  \
            for (int r = 0; r < 16; ++r) {                                     \
                o[dt][r] *= inv;                                               \
                mxd = fmaxf(mxd, o[dt][r]);                                    \
            }                                                                  \
        mxd = fmaxf(mxd, __shfl_xor(mxd, 32));                                 \
        float sd = 0.f;                                                        \
        _Pragma("unroll")                                                      \
        for (int dt = 0; dt < 4; ++dt)                                         \
            _Pragma("unroll")                                                  \
            for (int r = 0; r < 16; ++r) {                                     \
                float tv = __expf(o[dt][r] - mxd);                             \
                o[dt][r] = tv;                                                 \
                sd += tv;                                                      \
            }                                                                  \
        sd += __shfl_xor(sd, 32);                                              \
        float rinv = 1.f / sd;                                                 \
        float* orow = out + (size_t)(b * Sc + qg) * Dc + h * DHc;              \
        _Pragma("unroll")                                                      \
        for (int dt = 0; dt < 4; ++dt)                                         \
            _Pragma("unroll")                                                  \
            for (int g2 = 0; g2 < 4; ++g2) {                                   \
                f32x4 vv;                                                      \
                vv[0] = o[dt][4*g2+0] * rinv;                                  \
                vv[1] = o[dt][4*g2+1] * rinv;                                  \
                vv[2] = o[dt][4*g2+2] * rinv;                                  \
                vv[3] = o[dt][4*g2+3] * rinv;                                  \
                *(f32x4*)(orow + dt * 32 + g2 * 8 + half * 4) = vv;            \
            }                                                                  \
    } while (0)

// P(4 f32) -> v4h via 2x v_cvt_pkrtz (returns __fp16x2; elementwise assign)
#define PK4(dst_, s_, base_) do {                                               \
        v2hf _lo = __builtin_amdgcn_cvt_pkrtz((s_)[(base_)], (s_)[(base_)+1]);  \
        v2hf _hi = __builtin_amdgcn_cvt_pkrtz((s_)[(base_)+2], (s_)[(base_)+3]);\
        dst_[0] = (f16)_lo[0]; dst_[1] = (f16)_lo[1];                           \
        dst_[2] = (f16)_hi[0]; dst_[3] = (f16)_hi[1];                           \
    } while (0)

    const int tp_end = 2 * p + 2;
    const int tailoff = 15 - 2 * p;

    int qt = grp ? p : (15 - p);
    int q0 = qt * 128 + wg * 32;
    int qg = q0 + l31;

    v8h qf[8];
    {
        const f16* qrow = qh + bhoff + (size_t)qg * DHc;
        #pragma unroll
        for (int s = 0; s < 8; ++s)
            qf[s] = *(const v8h*)(qrow + s * 16 + half * 8);
    }

    float l_run = 0.f;
    v16f o[4];
    #pragma unroll
    for (int i = 0; i < 4; ++i)
        #pragma unroll
        for (int r = 0; r < 16; ++r) o[i][r] = 0.f;

    STAGE(0, 0);

    #pragma unroll 1
    for (int i = 0; i < 17; ++i) {
        __syncthreads();
        if (i < 16) {
            int inx = i + 1;
            int kn = (grp == 0) ? inx : ((inx < tp_end) ? inx : inx + tailoff);
            STAGE(kn, inx & 1);
        }
        if (grp == 1 && i == tp_end) {
            EPILOG;
            l_run = 0.f;
            #pragma unroll
            for (int d2 = 0; d2 < 4; ++d2)
                #pragma unroll
                for (int r = 0; r < 16; ++r) o[d2][r] = 0.f;
            qt = 15 - p; q0 = qt * 128 + wg * 32; qg = q0 + l31;
            const f16* qrow = qh + bhoff + (size_t)qg * DHc;
            #pragma unroll
            for (int s = 0; s < 8; ++s)
                qf[s] = *(const v8h*)(qrow + s * 16 + half * 8);
        }
        const int kv = (grp == 0) ? i : ((i < tp_end) ? i : i + tailoff);
        if (q0 + 31 < kv * 64) continue;

        const f16* kbuf = ksm + (i & 1) * 8192;
        const f16* vbuf = vsm + (i & 1) * 8192;
        const bool do1 = (kv * 64 + 32 <= q0 + 31);

        v16f st0, st1;
        #pragma unroll
        for (int r = 0; r < 16; ++r) { st0[r] = 0.f; st1[r] = 0.f; }
        #pragma unroll
        for (int s = 0; s < 8; ++s) {
            int c = ((s * 2 + half) ^ sw) * 8;
            v8h kf0 = *(const v8h*)(kbuf + l31 * 128 + c);
            st0 = __builtin_amdgcn_mfma_f32_32x32x16_f16(kf0, qf[s], st0, 0, 0, 0);
            if (do1) {
                v8h kf1 = *(const v8h*)(kbuf + (32 + l31) * 128 + c);
                st1 = __builtin_amdgcn_mfma_f32_32x32x16_f16(kf1, qf[s], st1, 0, 0, 0);
            }
        }

        float sum = 0.f;
        #pragma unroll
        for (int r = 0; r < 16; ++r) {
            int key = kv * 64 + (r & 3) + 8 * (r >> 2) + 4 * half;
            float sv = (key > qg) ? -1e30f : st0[r];
            float pe = __expf(sv);
            st0[r] = pe; sum += pe;
        }
        if (do1) {
            #pragma unroll
            for (int r = 0; r < 16; ++r) {
                int key = kv * 64 + 32 + (r & 3) + 8 * (r >> 2) + 4 * half;
                float sv = (key > qg) ? -1e30f : st1[r];
                float pe = __expf(sv);
                st1[r] = pe; sum += pe;
            }
        }
        sum += __shfl_xor(sum, 32);
        l_run += sum;

        #pragma unroll
        for (int s2 = 0; s2 < 4; ++s2) {
            v4h bfr;
            PK4(bfr, st0, 4 * s2);
            int c = ((s2 ^ sw) * 8) + half * 4;
            #pragma unroll
            for (int dt = 0; dt < 4; ++dt) {
                v4h vf = *(const v4h*)(vbuf + (dt * 32 + l31) * 64 + c);
                o[dt] = __builtin_amdgcn_mfma_f32_32x32x8f16(vf, bfr, o[dt], 0, 0, 0);
            }
        }
        if (do1) {
            #pragma unroll
            for (int s2 = 0; s2 < 4; ++s2) {
                v4h bfr;
                PK4(bfr, st1, 4 * s2);
                int c = (((4 + s2) ^ sw) * 8) + half * 4;
                #pragma unroll
                for (int dt = 0; dt < 4; ++dt) {
                    v4h vf = *(const v4h*)(vbuf + (dt * 32 + l31) * 64 + c);
                    o[dt] = __builtin_amdgcn_mfma_f32_32x32x8f16(vf, bfr, o[dt], 0, 0, 0);
                }
            }
        }
    }

    // ---- combine: g1's tile-A partial -> g0, then g0 epilogues tile A ----
    __syncthreads();
    float* ox = (float*)smem;
    float* lx = (float*)smem + 16384;
    if (grp == 1) {
        #pragma unroll
        for (int dt = 0; dt < 4; ++dt)
            #pragma unroll
            for (int r = 0; r < 16; ++r)
                ox[wg * 4096 + (dt * 16 + r) * 64 + lane] = o[dt][r];
        lx[wg * 64 + lane] = l_run;
    }
    __syncthreads();
    if (grp == 0) {
        #pragma unroll
        for (int dt = 0; dt < 4; ++dt)
            #pragma unroll
            for (int r = 0; r < 16; ++r)
                o[dt][r] += ox[wg * 4096 + (dt * 16 + r) * 64 + lane];
        l_run += lx[wg * 64 + lane];
        EPILOG;
    }
#undef STAGE
#undef EPILOG
#undef PK4
}

extern "C" void kernel_launch(void* const* d_in, const int* in_sizes, int n_in,
                              void* d_out, int out_size, void* d_ws, size_t ws_size,
                              hipStream_t stream)
{
    const float* x  = (const float*)d_in[0];
    const float* wq = (const float*)d_in[1];
    const float* wk = (const float*)d_in[2];
    const float* wv = (const float*)d_in[3];
    const float* cs = (const float*)d_in[4];
    const float* sn = (const float*)d_in[5];
    float* out = (float*)d_out;

    const size_t tsz = (size_t)Bc * Hc * Sc * DHc;   // 8,388,608 halves
    f16* qh = (f16*)d_ws;
    f16* kh = qh + tsz;
    f16* vt = kh + tsz;

    if (ws_size >= 11 * tsz) {
        f16* xh  = vt + tsz;
        f16* wqh = xh + tsz;
        f16* wkh = wqh + tsz / 2;
        f16* wvh = wkh + tsz / 2;
        cvt_kernel<<<2048, 256, 0, stream>>>(x, wq, wk, wv, xh, wqh, wkh, wvh);
        // wqh/wkh/wvh are contiguous -> one stacked-W GEMM, N = 6144
        proj256_kernel<<<768, 512, 0, stream>>>(xh, wqh, cs, sn, qh, kh, vt);
    } else {
        proj_kernel<<<dim3(32, 16, 3), 256, 0, stream>>>(x, wq, wk, wv, qh, kh, vt);
        rope_kernel<<<dim3(16384, 2), 256, 0, stream>>>(qh, kh, cs, sn);
    }
    attn_kernel<<<256, 512, 0, stream>>>(qh, kh, vt, out);
}